// Round 1
// baseline (666.432 us; speedup 1.0000x reference)
//
#include <hip/hip_runtime.h>
#include <hip/hip_bf16.h>

// Problem constants (reference: B,K,N,F,H = 20000,10,100000,256,128)
constexpr int B_ = 20000;
constexpr int K_ = 10;
constexpr int N_ = 100000;
constexpr int F_ = 256;
constexpr int H_ = 128;
constexpr int MT = 32;   // nodes per block in proj phase (N_ % MT == 0)

__device__ __forceinline__ float fast_tanh(float x) {
  // tanh(x) = 1 - 2/(e^{2x}+1); v_exp + v_rcp, ~1e-6 abs error, saturates correctly
  float e = __expf(2.0f * x);
  return 1.0f - 2.0f * __builtin_amdgcn_rcpf(e + 1.0f);
}

// ---------------------------------------------------------------------------
// Phase 1: per-node projections  q/k/v[n] = tanh(E[n] @ Wa) @ Wb   (bf16 out)
// Block: 256 threads, MT=32 nodes. Thread owns 2 h-values (hp, hp+64) x 8 nodes.
// x-tile in LDS (broadcast ds_read_b128: 8 FMAs per LDS read -> FMA-bound),
// weights streamed from global (L2-resident, ~590KB/block).
// ---------------------------------------------------------------------------
__global__ __launch_bounds__(256) void proj_kernel(
    const float* __restrict__ E,
    const float* __restrict__ W1a, const float* __restrict__ W1b,
    const float* __restrict__ W2a, const float* __restrict__ W2b,
    const float* __restrict__ W3a, const float* __restrict__ W3b,
    __hip_bfloat16* __restrict__ qo, __hip_bfloat16* __restrict__ ko,
    __hip_bfloat16* __restrict__ vo) {
  __shared__ __align__(16) float xs[MT * F_];  // 32 KB
  __shared__ __align__(16) float ts[MT * H_];  // 16 KB
  const int tid = threadIdx.x;
  const float* Wa[3] = {W1a, W2a, W3a};
  const float* Wb[3] = {W1b, W2b, W3b};
  __hip_bfloat16* Po[3] = {qo, ko, vo};

  // stage x tile: layout identical to global, coalesced float4 copy
  {
    const float4* Eg = (const float4*)(E + (size_t)blockIdx.x * (MT * F_));
    float4* xs4 = (float4*)xs;
#pragma unroll
    for (int i = 0; i < (MT * F_ / 4) / 256; ++i)
      xs4[tid + 256 * i] = Eg[tid + 256 * i];
  }
  __syncthreads();

  const int hp = tid & 63;   // lanes -> consecutive h (coalesced w loads/stores)
  const int g = tid >> 6;    // wave id -> node subset (wave-uniform LDS broadcast)

  for (int p = 0; p < 3; ++p) {
    // ---- layer 1: u[m][h] = sum_f x[m][f] * Wa[p][f][h]
    float acc[2][8];
#pragma unroll
    for (int a = 0; a < 2; ++a)
#pragma unroll
      for (int m = 0; m < 8; ++m) acc[a][m] = 0.0f;

    const float* __restrict__ wa = Wa[p];
    for (int fc = 0; fc < F_ / 4; ++fc) {
      const int f0 = fc * 4;
      float w[2][4];
#pragma unroll
      for (int a = 0; a < 2; ++a) {
        const int h = hp + 64 * a;
#pragma unroll
        for (int ff = 0; ff < 4; ++ff) w[a][ff] = wa[(f0 + ff) * H_ + h];
      }
#pragma unroll
      for (int mi = 0; mi < 8; ++mi) {
        const float4 xv = *(const float4*)&xs[(g + 4 * mi) * F_ + f0];
#pragma unroll
        for (int a = 0; a < 2; ++a) {
          acc[a][mi] = fmaf(xv.x, w[a][0], acc[a][mi]);
          acc[a][mi] = fmaf(xv.y, w[a][1], acc[a][mi]);
          acc[a][mi] = fmaf(xv.z, w[a][2], acc[a][mi]);
          acc[a][mi] = fmaf(xv.w, w[a][3], acc[a][mi]);
        }
      }
    }

    __syncthreads();  // previous projection's ts reads complete
#pragma unroll
    for (int a = 0; a < 2; ++a)
#pragma unroll
      for (int mi = 0; mi < 8; ++mi)
        ts[(g + 4 * mi) * H_ + hp + 64 * a] = fast_tanh(acc[a][mi]);
    __syncthreads();

    // ---- layer 2: p[m][h] = sum_f t[m][f] * Wb[p][f][h]
    float ac2[2][8];
#pragma unroll
    for (int a = 0; a < 2; ++a)
#pragma unroll
      for (int m = 0; m < 8; ++m) ac2[a][m] = 0.0f;

    const float* __restrict__ wb = Wb[p];
    for (int fc = 0; fc < H_ / 4; ++fc) {
      const int f0 = fc * 4;
      float w[2][4];
#pragma unroll
      for (int a = 0; a < 2; ++a) {
        const int h = hp + 64 * a;
#pragma unroll
        for (int ff = 0; ff < 4; ++ff) w[a][ff] = wb[(f0 + ff) * H_ + h];
      }
#pragma unroll
      for (int mi = 0; mi < 8; ++mi) {
        const float4 tv = *(const float4*)&ts[(g + 4 * mi) * H_ + f0];
#pragma unroll
        for (int a = 0; a < 2; ++a) {
          ac2[a][mi] = fmaf(tv.x, w[a][0], ac2[a][mi]);
          ac2[a][mi] = fmaf(tv.y, w[a][1], ac2[a][mi]);
          ac2[a][mi] = fmaf(tv.z, w[a][2], ac2[a][mi]);
          ac2[a][mi] = fmaf(tv.w, w[a][3], ac2[a][mi]);
        }
      }
    }

    __hip_bfloat16* __restrict__ o = Po[p];
#pragma unroll
    for (int a = 0; a < 2; ++a)
#pragma unroll
      for (int mi = 0; mi < 8; ++mi) {
        const int n = blockIdx.x * MT + g + 4 * mi;
        o[n * H_ + hp + 64 * a] = __float2bfloat16(ac2[a][mi]);
      }
  }
}

// ---------------------------------------------------------------------------
// Phase 2: per-batch-node attention aggregate.
// out[b,d] = sum_j colsum[j] * v[j,d], colsum[j] = sum_i softmax_j(q_i.k_j)
// One block (128 threads) per b; gather 3x10 rows of 128 bf16 from workspace.
// ---------------------------------------------------------------------------
__global__ __launch_bounds__(128) void agg_kernel(
    const int* __restrict__ nbr,
    const __hip_bfloat16* __restrict__ qa,
    const __hip_bfloat16* __restrict__ ka,
    const __hip_bfloat16* __restrict__ va,
    float* __restrict__ out) {
  constexpr int RS = 132;  // padded row stride in floats (16B-aligned rows)
  __shared__ __align__(16) float qs[K_ * RS];
  __shared__ __align__(16) float ks[K_ * RS];
  __shared__ __align__(16) float vs[K_ * RS];
  __shared__ float sc[K_ * 12];
  __shared__ float colw[K_];
  const int b = blockIdx.x;
  const int tid = threadIdx.x;

  // neighbor ids are lane-invariant -> scalar loads
  int nb[K_];
#pragma unroll
  for (int i = 0; i < K_; ++i) nb[i] = nbr[b * K_ + i];

#pragma unroll
  for (int i = 0; i < K_; ++i) {
    const int off = nb[i] * H_ + tid;
    qs[i * RS + tid] = __bfloat162float(qa[off]);
    ks[i * RS + tid] = __bfloat162float(ka[off]);
    vs[i * RS + tid] = __bfloat162float(va[off]);
  }
  __syncthreads();

  // scores: thread (i,j) for tid < 100
  if (tid < K_ * K_) {
    const int i = tid / K_;
    const int j = tid - i * K_;
    const float4* q4 = (const float4*)&qs[i * RS];
    const float4* k4 = (const float4*)&ks[j * RS];
    float s = 0.0f;
#pragma unroll
    for (int d = 0; d < H_ / 4; ++d) {
      const float4 a = q4[d];
      const float4 c = k4[d];
      s = fmaf(a.x, c.x, s);
      s = fmaf(a.y, c.y, s);
      s = fmaf(a.z, c.z, s);
      s = fmaf(a.w, c.w, s);
    }
    sc[i * 12 + j] = s;
  }
  __syncthreads();

  // softmax along j, per row i
  if (tid < K_) {
    float m = sc[tid * 12 + 0];
#pragma unroll
    for (int j = 1; j < K_; ++j) m = fmaxf(m, sc[tid * 12 + j]);
    float e[K_];
    float sum = 0.0f;
#pragma unroll
    for (int j = 0; j < K_; ++j) {
      e[j] = __expf(sc[tid * 12 + j] - m);
      sum += e[j];
    }
    const float inv = __builtin_amdgcn_rcpf(sum);
#pragma unroll
    for (int j = 0; j < K_; ++j) sc[tid * 12 + j] = e[j] * inv;
  }
  __syncthreads();

  // column sums of att
  if (tid < K_) {
    float c = 0.0f;
#pragma unroll
    for (int i = 0; i < K_; ++i) c += sc[i * 12 + tid];
    colw[tid] = c;
  }
  __syncthreads();

  // out[b,d] = sum_j colw[j] * v[j,d]
  float o = 0.0f;
#pragma unroll
  for (int j = 0; j < K_; ++j) o = fmaf(colw[j], vs[j * RS + tid], o);
  out[(size_t)b * H_ + tid] = o;
}

extern "C" void kernel_launch(void* const* d_in, const int* in_sizes, int n_in,
                              void* d_out, int out_size, void* d_ws, size_t ws_size,
                              hipStream_t stream) {
  const int* nbr = (const int*)d_in[0];
  const float* E = (const float*)d_in[1];
  const float* W1a = (const float*)d_in[2];
  const float* W1b = (const float*)d_in[3];
  const float* W2a = (const float*)d_in[4];
  const float* W2b = (const float*)d_in[5];
  const float* W3a = (const float*)d_in[6];
  const float* W3b = (const float*)d_in[7];
  float* out = (float*)d_out;

  // workspace: q/k/v per-node projections, bf16 [N,H] each = 76.8 MB total
  __hip_bfloat16* qa = (__hip_bfloat16*)d_ws;
  __hip_bfloat16* ka = qa + (size_t)N_ * H_;
  __hip_bfloat16* va = ka + (size_t)N_ * H_;

  proj_kernel<<<N_ / MT, 256, 0, stream>>>(E, W1a, W1b, W2a, W2b, W3a, W3b,
                                           qa, ka, va);
  agg_kernel<<<B_, 128, 0, stream>>>(nbr, qa, ka, va, out);
}

// Round 2
// 279.781 us; speedup vs baseline: 2.3820x; 2.3820x over previous
//
#include <hip/hip_runtime.h>
#include <hip/hip_bf16.h>

// Problem constants (reference: B,K,N,F,H = 20000,10,100000,256,128)
constexpr int B_ = 20000;
constexpr int K_ = 10;
constexpr int N_ = 100000;
constexpr int F_ = 256;
constexpr int H_ = 128;

typedef __attribute__((ext_vector_type(8))) short bf16x8;
typedef __attribute__((ext_vector_type(4))) float f32x4;
typedef __attribute__((ext_vector_type(4))) unsigned short ushort4v;

__device__ __forceinline__ unsigned short f2bf(float x) {
  // round-to-nearest-even fp32 -> bf16
  unsigned int u = __builtin_bit_cast(unsigned int, x);
  unsigned int r = u + 0x7fffu + ((u >> 16) & 1u);
  return (unsigned short)(r >> 16);
}

__device__ __forceinline__ float fast_tanh(float x) {
  float e = __expf(2.0f * x);
  return 1.0f - 2.0f * __builtin_amdgcn_rcpf(e + 1.0f);
}

// ---------------------------------------------------------------------------
// Prep: bf16-transpose the six weight matrices.
// wat[p][h][k] = Wa_p[k][h]  (3 x 128 x 256)
// wbt[p][h][k] = Wb_p[k][h]  (3 x 128 x 128)
// Writes coalesced; reads strided (L2-resident, 590 KB total).
// ---------------------------------------------------------------------------
__global__ __launch_bounds__(256) void prep_kernel(
    const float* __restrict__ W1a, const float* __restrict__ W1b,
    const float* __restrict__ W2a, const float* __restrict__ W2b,
    const float* __restrict__ W3a, const float* __restrict__ W3b,
    unsigned short* __restrict__ wat, unsigned short* __restrict__ wbt) {
  const float* Wa[3] = {W1a, W2a, W3a};
  const float* Wb[3] = {W1b, W2b, W3b};
  int g = blockIdx.x * 256 + threadIdx.x;
  if (g < 3 * F_ * H_) {
    int p = g >> 15;            // / 32768
    int r = g & (F_ * H_ - 1);  // % 32768
    int h = r >> 8;             // / 256
    int k = r & 255;
    wat[g] = f2bf(Wa[p][k * H_ + h]);
  } else {
    int g2 = g - 3 * F_ * H_;
    int p = g2 >> 14;
    int r = g2 & (H_ * H_ - 1);
    int h = r >> 7;
    int k = r & 127;
    wbt[g2] = f2bf(Wb[p][k * H_ + h]);
  }
}

// ---------------------------------------------------------------------------
// Phase 1 (MFMA): per-node q/k/v projections.
// Block = 256 threads (4 waves), MT=64 nodes. Wave w owns output cols
// [32w, 32w+32) -> each weight element read exactly once per block (B-frags
// straight from L2-hot global WT). X tile fp32->bf16 in LDS; A-frags via
// ds_read_b128. mfma_f32_16x16x32_bf16, fp32 accum.
// ---------------------------------------------------------------------------
constexpr int MT = 64;
constexpr int XS = F_ + 8;  // 264: row stride (528 B, 16B-aligned, conflict-safe)
constexpr int TS = H_ + 8;  // 136: row stride (272 B)

__global__ __launch_bounds__(256, 3) void proj_kernel(
    const float* __restrict__ E,
    const unsigned short* __restrict__ wat,
    const unsigned short* __restrict__ wbt,
    unsigned short* __restrict__ qo, unsigned short* __restrict__ ko,
    unsigned short* __restrict__ vo) {
  __shared__ unsigned short xs[MT * XS];  // 33 KB
  __shared__ unsigned short ts[MT * TS];  // 17 KB

  const int tid = threadIdx.x;
  const int lane = tid & 63;
  const int w = tid >> 6;     // wave id: output col group [32w, 32w+32)
  const int l15 = lane & 15;
  const int kg = lane >> 4;   // k-subgroup 0..3
  const int row0 = blockIdx.x * MT;

  // ---- stage X tile (fp32 global -> bf16 LDS), zero-pad OOB rows
  {
    const float4* Eg = (const float4*)E;
#pragma unroll
    for (int it = 0; it < 16; ++it) {
      int i = tid + 256 * it;       // float4 index within tile
      int r = i >> 6;               // row (64 float4 per row)
      int c4 = i & 63;
      float4 v = make_float4(0.f, 0.f, 0.f, 0.f);
      if (row0 + r < N_) v = Eg[(size_t)(row0 + r) * (F_ / 4) + c4];
      ushort4v o;
      o.x = f2bf(v.x); o.y = f2bf(v.y); o.z = f2bf(v.z); o.w = f2bf(v.w);
      *(ushort4v*)&xs[r * XS + c4 * 4] = o;
    }
  }
  __syncthreads();

  unsigned short* const outp[3] = {qo, ko, vo};

  for (int p = 0; p < 3; ++p) {
    const unsigned short* __restrict__ wap = wat + p * (F_ * H_);
    const unsigned short* __restrict__ wbp = wbt + p * (H_ * H_);

    // ---- layer 1: U = X @ Wa   (K=256, 8 k-steps)
    f32x4 acc1[4][2];
#pragma unroll
    for (int rt = 0; rt < 4; ++rt)
#pragma unroll
      for (int c = 0; c < 2; ++c) acc1[rt][c] = (f32x4)0.0f;

#pragma unroll
    for (int k = 0; k < 8; ++k) {
      const int koff = k * 32 + kg * 8;
      bf16x8 b0 = *(const bf16x8*)&wap[(w * 32 + l15) * F_ + koff];
      bf16x8 b1 = *(const bf16x8*)&wap[(w * 32 + 16 + l15) * F_ + koff];
#pragma unroll
      for (int rt = 0; rt < 4; ++rt) {
        bf16x8 a = *(const bf16x8*)&xs[(rt * 16 + l15) * XS + koff];
        acc1[rt][0] = __builtin_amdgcn_mfma_f32_16x16x32_bf16(a, b0, acc1[rt][0], 0, 0, 0);
        acc1[rt][1] = __builtin_amdgcn_mfma_f32_16x16x32_bf16(a, b1, acc1[rt][1], 0, 0, 0);
      }
    }

    __syncthreads();  // prior projection's ts reads complete
    // tanh + scatter to ts (C/D layout: row=(lane>>4)*4+r, col=l15)
#pragma unroll
    for (int rt = 0; rt < 4; ++rt)
#pragma unroll
      for (int c = 0; c < 2; ++c)
#pragma unroll
        for (int r = 0; r < 4; ++r) {
          int m = rt * 16 + kg * 4 + r;
          int h = w * 32 + c * 16 + l15;
          ts[m * TS + h] = f2bf(fast_tanh(acc1[rt][c][r]));
        }
    __syncthreads();

    // ---- layer 2: P = T @ Wb   (K=128, 4 k-steps)
    f32x4 acc2[4][2];
#pragma unroll
    for (int rt = 0; rt < 4; ++rt)
#pragma unroll
      for (int c = 0; c < 2; ++c) acc2[rt][c] = (f32x4)0.0f;

#pragma unroll
    for (int k = 0; k < 4; ++k) {
      const int koff = k * 32 + kg * 8;
      bf16x8 b0 = *(const bf16x8*)&wbp[(w * 32 + l15) * H_ + koff];
      bf16x8 b1 = *(const bf16x8*)&wbp[(w * 32 + 16 + l15) * H_ + koff];
#pragma unroll
      for (int rt = 0; rt < 4; ++rt) {
        bf16x8 a = *(const bf16x8*)&ts[(rt * 16 + l15) * TS + koff];
        acc2[rt][0] = __builtin_amdgcn_mfma_f32_16x16x32_bf16(a, b0, acc2[rt][0], 0, 0, 0);
        acc2[rt][1] = __builtin_amdgcn_mfma_f32_16x16x32_bf16(a, b1, acc2[rt][1], 0, 0, 0);
      }
    }

    // ---- store P as bf16 (C/D layout -> [node][h])
    unsigned short* __restrict__ o = outp[p];
#pragma unroll
    for (int rt = 0; rt < 4; ++rt)
#pragma unroll
      for (int c = 0; c < 2; ++c)
#pragma unroll
        for (int r = 0; r < 4; ++r) {
          int n = row0 + rt * 16 + kg * 4 + r;
          if (n < N_) o[(size_t)n * H_ + w * 32 + c * 16 + l15] = f2bf(acc2[rt][c][r]);
        }
  }
}

// ---------------------------------------------------------------------------
// Phase 2: per-batch-node attention aggregate (unchanged from round 1).
// ---------------------------------------------------------------------------
__global__ __launch_bounds__(128) void agg_kernel(
    const int* __restrict__ nbr,
    const __hip_bfloat16* __restrict__ qa,
    const __hip_bfloat16* __restrict__ ka,
    const __hip_bfloat16* __restrict__ va,
    float* __restrict__ out) {
  constexpr int RS = 132;
  __shared__ __align__(16) float qs[K_ * RS];
  __shared__ __align__(16) float ks[K_ * RS];
  __shared__ __align__(16) float vs[K_ * RS];
  __shared__ float sc[K_ * 12];
  __shared__ float colw[K_];
  const int b = blockIdx.x;
  const int tid = threadIdx.x;

  int nb[K_];
#pragma unroll
  for (int i = 0; i < K_; ++i) nb[i] = nbr[b * K_ + i];

#pragma unroll
  for (int i = 0; i < K_; ++i) {
    const int off = nb[i] * H_ + tid;
    qs[i * RS + tid] = __bfloat162float(qa[off]);
    ks[i * RS + tid] = __bfloat162float(ka[off]);
    vs[i * RS + tid] = __bfloat162float(va[off]);
  }
  __syncthreads();

  if (tid < K_ * K_) {
    const int i = tid / K_;
    const int j = tid - i * K_;
    const float4* q4 = (const float4*)&qs[i * RS];
    const float4* k4 = (const float4*)&ks[j * RS];
    float s = 0.0f;
#pragma unroll
    for (int d = 0; d < H_ / 4; ++d) {
      const float4 a = q4[d];
      const float4 c = k4[d];
      s = fmaf(a.x, c.x, s);
      s = fmaf(a.y, c.y, s);
      s = fmaf(a.z, c.z, s);
      s = fmaf(a.w, c.w, s);
    }
    sc[i * 12 + j] = s;
  }
  __syncthreads();

  if (tid < K_) {
    float m = sc[tid * 12 + 0];
#pragma unroll
    for (int j = 1; j < K_; ++j) m = fmaxf(m, sc[tid * 12 + j]);
    float e[K_];
    float sum = 0.0f;
#pragma unroll
    for (int j = 0; j < K_; ++j) {
      e[j] = __expf(sc[tid * 12 + j] - m);
      sum += e[j];
    }
    const float inv = __builtin_amdgcn_rcpf(sum);
#pragma unroll
    for (int j = 0; j < K_; ++j) sc[tid * 12 + j] = e[j] * inv;
  }
  __syncthreads();

  if (tid < K_) {
    float c = 0.0f;
#pragma unroll
    for (int i = 0; i < K_; ++i) c += sc[i * 12 + tid];
    colw[tid] = c;
  }
  __syncthreads();

  float o = 0.0f;
#pragma unroll
  for (int j = 0; j < K_; ++j) o = fmaf(colw[j], vs[j * RS + tid], o);
  out[(size_t)b * H_ + tid] = o;
}

extern "C" void kernel_launch(void* const* d_in, const int* in_sizes, int n_in,
                              void* d_out, int out_size, void* d_ws, size_t ws_size,
                              hipStream_t stream) {
  const int* nbr = (const int*)d_in[0];
  const float* E = (const float*)d_in[1];
  const float* W1a = (const float*)d_in[2];
  const float* W1b = (const float*)d_in[3];
  const float* W2a = (const float*)d_in[4];
  const float* W2b = (const float*)d_in[5];
  const float* W3a = (const float*)d_in[6];
  const float* W3b = (const float*)d_in[7];
  float* out = (float*)d_out;

  // workspace layout:
  //   qa/ka/va : 3 x [N,H] bf16 = 76.8 MB
  //   wat      : 3 x [H=128][K=256] bf16 (transposed Wa)
  //   wbt      : 3 x [H=128][K=128] bf16 (transposed Wb)
  unsigned short* qa = (unsigned short*)d_ws;
  unsigned short* ka = qa + (size_t)N_ * H_;
  unsigned short* va = ka + (size_t)N_ * H_;
  unsigned short* wat = va + (size_t)N_ * H_;
  unsigned short* wbt = wat + (size_t)3 * F_ * H_;

  prep_kernel<<<(3 * F_ * H_ + 3 * H_ * H_) / 256, 256, 0, stream>>>(
      W1a, W1b, W2a, W2b, W3a, W3b, wat, wbt);
  proj_kernel<<<(N_ + MT - 1) / MT, 256, 0, stream>>>(E, wat, wbt, qa, ka, va);
  agg_kernel<<<B_, 128, 0, stream>>>(
      nbr, (const __hip_bfloat16*)qa, (const __hip_bfloat16*)ka,
      (const __hip_bfloat16*)va, out);
}